// Round 12
// baseline (209.377 us; speedup 1.0000x reference)
//
#include <hip/hip_runtime.h>
#include <hip/hip_bf16.h>

// Problem constants (reference: B=2, N=20000, K=16, DIM=256)
// Established facts (R1-R22):
//   - float tensors fp32; idx int32/int64 runtime-detected; d_out fp32
//   - MFMA 16x16x32_bf16 gemm-BT fragments + C/D map verified
//   - R5-R8: global->VGPR weight loads serialize; use LDS (DMA) for weights.
//   - R11: final weight-stationary col-HALF (250x512, 128 KB LDS) = 39.4 us.
//     KNOWN GOOD. R17 col-quarter REGRESSED (4x A re-reads NOT L3-absorbed).
//   - R12-R14: dispatches latency/ramp-bound; co-dispatch of independent
//     work is the only fusion that wins (R14 = 195.8 BEST).
//   - R15 REGRESSION: gather2-in-final (dup work + L2 thrash).
//   - R16 REGRESSION: 128KB-LDS coop mega-kernel capped gather occupancy.
//   - R18: 2-pt/thread gathers REGRESSED (halved latency streams).
//   - R19 FAILED correctness: coop gather12 merge (grid.sync between
//     dependent phases under graph capture). Banned without probe.
//   - R20/R21: dest-linear Wnt convert REGRESSED stage2 43->89.7 (lanes
//     share n -> ~16-way write conflict + lost load burst); thread-major
//     form restored -> 43.0 us confirmed. Zero in one counter != faster.
//   - R22 (this round): gather2 split by COLUMN half. g2a (x2 geom cols ->
//     x3[:,128:192]) depends only on stage2 -> CO-DISPATCHED with gather1
//     (disjoint outputs). g2b (x2 gather cols -> x3[:,192:256]) after g1.
//     Chain: stage2 -> gatherA[g1||g2a] -> gatherB[g2b] -> final. Critical
//     path: g1 + g2_full -> packed(g1,g2a) + g2b. All bodies = gather1's
//     proven 8-lane dual-idx shape, offsets only.
//   - LDS quarter-wave phasing: byte addr = r*16 + q*(multiple of 1 KB) +
//     const is conflict-free (R9/R11 measured 0).
#define BN   40000
#define NPTS 20000
#define KNN  16
#define DIM  256

typedef __attribute__((ext_vector_type(8))) short bf16x8;   // 8 bf16 = 4 VGPRs
typedef __attribute__((ext_vector_type(4))) float f32x4;
typedef __attribute__((ext_vector_type(16))) float f32x16;

__device__ __forceinline__ float lrelu(float v) { return fmaxf(v, 0.1f * v); }
__device__ __forceinline__ float bs2f(short s) {
    union { unsigned u; float f; } c; c.u = ((unsigned)(unsigned short)s) << 16;
    return c.f;
}
__device__ __forceinline__ short f2bs(float f) {
    __hip_bfloat16 h = __float2bfloat16(f);           // RNE
    return *reinterpret_cast<short*>(&h);
}

// async global->LDS, 16 B per lane; lds dst = wave-uniform base + lane*16.
__device__ __forceinline__ void dma16(const void* g, void* l) {
    __builtin_amdgcn_global_load_lds(
        (const __attribute__((address_space(1))) unsigned int*)g,
        (__attribute__((address_space(3))) unsigned int*)l, 16, 0, 0);
}

// gather-mean core: 8 lanes/point, dual-idx, 8 k-iters x 2 neighbors.
// Reads 16B per lane from src row (srcoff..srcoff+64 cols covered by j*8),
// accumulates 16-neighbor mean, writes bf16x8 to dst row at dstoff.
__device__ __forceinline__ void gather8(
    const int* __restrict__ idxw, int dual, int t, int lane,
    const short* __restrict__ src, int src_stride, int src_coloff,
    short* __restrict__ dst, int dst_stride, int dst_coloff)
{
    int p = t >> 3, j = t & 7;
    int base = (p >= NPTS) ? NPTS : 0;
    int i0 = idxw[((size_t)p * 16 + 2*j)     * dual];   // neighbor 2j
    int i1 = idxw[((size_t)p * 16 + 2*j + 1) * dual];   // neighbor 2j+1
    int g8 = lane & 56;
    float acc[8];
#pragma unroll
    for (int i = 0; i < 8; ++i) acc[i] = 0.f;
#pragma unroll
    for (int k = 0; k < 8; ++k) {
        int rA = base + __shfl(i0, g8 + k, 64);         // neighbor 2k
        int rB = base + __shfl(i1, g8 + k, 64);         // neighbor 2k+1
        bf16x8 vA = *(const bf16x8*)(src + (size_t)rA * src_stride + src_coloff + j * 8);
        bf16x8 vB = *(const bf16x8*)(src + (size_t)rB * src_stride + src_coloff + j * 8);
#pragma unroll
        for (int i = 0; i < 8; ++i) acc[i] += bs2f(vA[i]) + bs2f(vB[i]);
    }
    bf16x8 o;
#pragma unroll
    for (int i = 0; i < 8; ++i) o[i] = f2bs(acc[i] * (1.f/16.f));
    *(bf16x8*)(dst + (size_t)p * dst_stride + dst_coloff + j * 8) = o;
}

// ---------------------------------------------------------------------------
// stage2: geom MLPs (blocks 0..624) + mlp_init (625..1249) + Wt weight
// conversion (1250..1377) + idx-dtype detect (1378). All mutually
// independent inside this dispatch:
//   geom: reads geom,W1,W2 -> x2[:,0:64], x3[:,0:128]
//   mlp:  reads input, Wn (self-converted to LDS, thread-major), b_init -> x1
//   conv: Wf,Wi -> tiled Wt (consumed by final, 3 dispatches later)
//   detect: -> flag (consumed by gatherA, next dispatch)
// ---------------------------------------------------------------------------
__global__ void __launch_bounds__(256) stage2_kernel(
    const float* __restrict__ geom,      // [BN,16,4]
    const float* __restrict__ W1, const float* __restrict__ B1,   // [64,4],[64]
    const float* __restrict__ W2, const float* __restrict__ B2,   // [128,4],[128]
    const float* __restrict__ X,         // [BN,256] input
    const float* __restrict__ Wn,        // [64,256] W_init fp32
    const float* __restrict__ b_init,    // [64]
    const int* __restrict__ idxw,
    const float* __restrict__ Wf, const float* __restrict__ Wi,   // [256,256]
    short* __restrict__ Wt, int* __restrict__ flag,
    __hip_bfloat16* __restrict__ x2,     // [BN,128]
    __hip_bfloat16* __restrict__ x3,     // [BN,256]
    __hip_bfloat16* __restrict__ x1)     // [BN,64] bf16 (d_out scratch)
{
    __shared__ short wbuf[16384];        // 32 KB (mlp blocks only)

    if (blockIdx.x >= 1250) {
        if (blockIdx.x == 1378) {        // ---- detect block (no atomics) ----
            __shared__ int red[256];
            int t = threadIdx.x;
            int v = 0;
#pragma unroll
            for (int it = 0; it < 64; ++it)
                v |= idxw[2 * (t + it * 256) + 1];   // odd words, first 128 KB
            red[t] = v;
            __syncthreads();
            for (int s = 128; s > 0; s >>= 1) {
                if (t < s) red[t] |= red[t + s];
                __syncthreads();
            }
            if (t == 0) *flag = (red[0] != 0) ? 1 : 0;
            return;
        }
        // ---- Wt conversion blocks: Wf (t<16384) / Wi -> tiled Wt ----
        int t = (blockIdx.x - 1250) * 256 + threadIdx.x;   // < 32768 exactly
        int mat = (t >> 14) & 1;
        int tt  = t & 16383;
        float4 v = mat ? ((const float4*)Wi)[tt] : ((const float4*)Wf)[tt];
        int n  = tt >> 6;
        int k  = (tt & 63) * 4;
        int kk = k >> 5, q = (k >> 3) & 3, j = k & 7;
        short4 o; o.x=f2bs(v.x); o.y=f2bs(v.y); o.z=f2bs(v.z); o.w=f2bs(v.w);
        *(short4*)(Wt + ((size_t)((kk*2 + mat)*4 + q))*2048 + n*8 + j) = o;
        return;
    }

    if (blockIdx.x >= 625) {             // ---------------- mlp_init ----------
        int bid = blockIdx.x - 625;      // 0..624
        int t = threadIdx.x;
        int wave = t >> 6, lane = t & 63;
        int r = lane & 15, q = lane >> 4;
        // ---- self-convert W_init -> wbuf, THREAD-MAJOR (R18 exact form,
        // stage2=43.0 us measured; R20's dest-linear variant was 2x slower).
        {
            const float4* Wn4 = (const float4*)Wn;
#pragma unroll
            for (int i = 0; i < 16; ++i) {
                int tt = t * 16 + i;              // 0..4095
                float4 v = Wn4[tt];
                int n  = tt >> 6;
                int k  = (tt & 63) * 4;
                int kk = k >> 5, qq = (k >> 3) & 3, j = k & 7;
                short4 o; o.x=f2bs(v.x); o.y=f2bs(v.y); o.z=f2bs(v.z); o.w=f2bs(v.w);
                *(short4*)&wbuf[((kk*4 + qq)*64 + n)*8 + j] = o;
            }
        }
        int m0 = bid * 64 + wave * 16;
        const float4* X4 = (const float4*)(X + (size_t)(m0 + r) * DIM + q * 8);
        bf16x8 a[8];
        // burst 8 raw float4 loads, then convert (2 groups of 4 kk)
#pragma unroll
        for (int g = 0; g < 2; ++g) {
            float4 rwm[8];
#pragma unroll
            for (int kk = 0; kk < 4; ++kk) {
                rwm[2*kk]   = X4[(g*4 + kk) * 8];
                rwm[2*kk+1] = X4[(g*4 + kk) * 8 + 1];
            }
#pragma unroll
            for (int kk = 0; kk < 4; ++kk) {
                const float4 lo = rwm[2*kk], hi2 = rwm[2*kk+1];
                bf16x8 av;
                av[0]=f2bs(lo.x);  av[1]=f2bs(lo.y);  av[2]=f2bs(lo.z);  av[3]=f2bs(lo.w);
                av[4]=f2bs(hi2.x); av[5]=f2bs(hi2.y); av[6]=f2bs(hi2.z); av[7]=f2bs(hi2.w);
                a[g*4 + kk] = av;
            }
        }
        __syncthreads();                 // wbuf conversion writes visible

        f32x4 acc[4];
#pragma unroll
        for (int nt = 0; nt < 4; ++nt) acc[nt] = (f32x4){0.f,0.f,0.f,0.f};
#pragma unroll
        for (int kk = 0; kk < 8; ++kk) {
#pragma unroll
            for (int nt = 0; nt < 4; ++nt) {
                bf16x8 b = *(const bf16x8*)&wbuf[((kk*4 + q)*64 + nt*16 + r) * 8];
                acc[nt] = __builtin_amdgcn_mfma_f32_16x16x32_bf16(a[kk], b, acc[nt], 0, 0, 0);
            }
        }
#pragma unroll
        for (int nt = 0; nt < 4; ++nt) {
            int col = nt * 16 + r;
            float bvx = b_init[col];
#pragma unroll
            for (int i = 0; i < 4; ++i) {
                float v = lrelu(acc[nt][i] + bvx);
                x1[(size_t)(m0 + q*4 + i) * 64 + col] = __float2bfloat16(v);
            }
        }
        return;
    }

    // ---------------- geom: 625 blocks x 4 waves x 8 pairs = 40000 pts -----
    const int lane = threadIdx.x & 63;
    const int wv   = threadIdx.x >> 6;
    const int c31  = lane & 31;
    const int hi   = lane >> 5;
    const int wglob = blockIdx.x * 4 + wv;            // 0..2499

    // B-frags + biases: hoisted ONCE per wave.
    // tiles 0-1 = W1 (64 ch -> x2), 2-5 = W2 (128 ch -> x3)
    bf16x8 bfr[6]; float bv[6];
#pragma unroll
    for (int tt = 0; tt < 6; ++tt) {
        bfr[tt] = (bf16x8){0,0,0,0,0,0,0,0};
        const float* Wrow;
        if (tt < 2) { Wrow = W1 + (size_t)(tt*32 + c31) * 4;     bv[tt] = B1[tt*32 + c31]; }
        else        { Wrow = W2 + (size_t)((tt-2)*32 + c31) * 4; bv[tt] = B2[(tt-2)*32 + c31]; }
        if (hi == 0) {
            const float4 w4 = *(const float4*)Wrow;
            bfr[tt][0]=f2bs(w4.x); bfr[tt][1]=f2bs(w4.y);
            bfr[tt][2]=f2bs(w4.z); bfr[tt][3]=f2bs(w4.w);
        }
    }
    f32x16 ZR;
#pragma unroll
    for (int i = 0; i < 16; ++i) ZR[i] = 0.f;

    // prefetch pair 0's geom data
    float4 g = (float4){0.f,0.f,0.f,0.f};
    if (hi == 0)
        g = *(const float4*)(geom +
            ((size_t)((wglob * 8) * 2 + (c31 >> 4)) * KNN + (c31 & 15)) * 4);

#pragma unroll
    for (int it = 0; it < 8; ++it) {
        const int p0 = (wglob * 8 + it) * 2;
        const float4 gc = g;
        if (it < 7 && hi == 0)                        // prefetch next pair
            g = *(const float4*)(geom +
                ((size_t)(p0 + 2 + (c31 >> 4)) * KNN + (c31 & 15)) * 4);

        // A-frag: row = lane&31 -> (pt = row>>4, k = row&15); cols 0..3 real.
        bf16x8 a = (bf16x8){0,0,0,0,0,0,0,0};
        if (hi == 0) { a[0]=f2bs(gc.x); a[1]=f2bs(gc.y); a[2]=f2bs(gc.z); a[3]=f2bs(gc.w); }

        f32x16 acc[6];
#pragma unroll
        for (int tt = 0; tt < 6; ++tt)
            acc[tt] = __builtin_amdgcn_mfma_f32_32x32x16_bf16(a, bfr[tt], ZR, 0, 0, 0);

        // Epilogue: regs 0-7 -> pt A rows, 8-15 -> pt B rows; each lane covers
        // 8 of 16 rows of each point; shfl_xor(32) completes the mean.
#pragma unroll
        for (int tt = 0; tt < 6; ++tt) {
            float sA = 0.f, sB = 0.f;
#pragma unroll
            for (int i = 0; i < 8; ++i)  sA += lrelu(acc[tt][i]     + bv[tt]);
#pragma unroll
            for (int i = 0; i < 8; ++i)  sB += lrelu(acc[tt][i + 8] + bv[tt]);
            sA += __shfl_xor(sA, 32, 64);
            sB += __shfl_xor(sB, 32, 64);
            const float s = (hi ? sB : sA) * (1.f / 16.f);
            const short v = f2bs(s);
            if (tt < 2) ((short*)x2)[(size_t)(p0 + hi) * 128 + tt*32 + c31] = v;
            else        ((short*)x3)[(size_t)(p0 + hi) * 256 + (tt-2)*32 + c31] = v;
        }
    }
}

// ---------------------------------------------------------------------------
// gatherA: CO-DISPATCH of two independent gathers (both depend only on
// stage2 outputs):
//   blocks 0..1249:   g1  = mean of x1 rows   -> x2[:,64:128]
//   blocks 1250..2499: g2a = mean of x2[:,0:64] (geom half, stage2-written)
//                            -> x3[:,128:192]
// Disjoint outputs; g2a reads bytes g1 never writes. Both = proven 8-lane
// dual-idx gather shape.
// ---------------------------------------------------------------------------
__global__ void __launch_bounds__(256) gatherA_kernel(
    const int* __restrict__ idxw, const int* __restrict__ flag,
    const __hip_bfloat16* __restrict__ x1,    // [BN,64]
    __hip_bfloat16* __restrict__ x2,          // [BN,128]
    __hip_bfloat16* __restrict__ x3)          // [BN,256]
{
    int lane = threadIdx.x & 63;
    int dual = (*flag == 0) ? 2 : 1;
    if (blockIdx.x < 1250) {                  // ---- g1 ----
        int t = blockIdx.x * 256 + threadIdx.x;        // 320000 = BN*8
        gather8(idxw, dual, t, lane,
                (const short*)x1, 64, 0,
                (short*)x2, 128, 64);
    } else {                                  // ---- g2a ----
        int t = (blockIdx.x - 1250) * 256 + threadIdx.x;
        gather8(idxw, dual, t, lane,
                (const short*)x2, 128, 0,
                (short*)x3, 256, 128);
    }
}

// ---------------------------------------------------------------------------
// gatherB: g2b = mean of x2[:,64:128] (g1's output) -> x3[:,192:256].
// ---------------------------------------------------------------------------
__global__ void __launch_bounds__(256) gatherB_kernel(
    const int* __restrict__ idxw, const int* __restrict__ flag,
    const __hip_bfloat16* __restrict__ x2,    // [BN,128]
    __hip_bfloat16* __restrict__ x3)          // [BN,256]
{
    int lane = threadIdx.x & 63;
    int dual = (*flag == 0) ? 2 : 1;
    int t = blockIdx.x * 256 + threadIdx.x;            // 320000 = BN*8
    gather8(idxw, dual, t, lane,
            (const short*)x2, 128, 64,
            (short*)x3, 256, 192);
}

// ---------------------------------------------------------------------------
// out = LR(x3 @ Wf^T + bf) + LR(input @ Wi^T + bi), fp32 out. MFMA.
// R11 weight-stationary col-HALF (KNOWN GOOD, 39.4 us):
//   grid = 250 = 2 col-halves x 125 row-chunks (320 rows each).
//   block = 512 thr (8 waves = 4 row-groups x 2 col-groups of 64 cols).
//   LDS 128 KB = col-half of BOTH mats, remapped from Wt as 64 x 2 KB chunks
//   [(mat*8+kk)*4+q][n_local<128][8], DMA'd ONCE (16 dma16/wave), ONE barrier.
//   Main loop: 5 tiles x 64 rows; A-frags (X3 bf16 direct, RES raw float4 +
//   lazy per-kk cvt) in regs; pure ds_read+MFMA; NO barriers, no W re-fetch.
//   B-read byte addr = const + q*2048 + r*16 -> quarter-wave conflict-free.
// ---------------------------------------------------------------------------
__global__ void __launch_bounds__(512, 2) final_mfma(
    const __hip_bfloat16* __restrict__ X3,    // [BN,256] bf16 ws
    const float* __restrict__ RES,            // [BN,256] fp32
    const short* __restrict__ Wt,             // tiled bf16 [kk][mat][q][n][8]
    const float* __restrict__ Bf,             // [256]
    const float* __restrict__ Bi,             // [256]
    float* __restrict__ OUT)                  // [BN,256] fp32
{
    __shared__ short lw[65536];               // 128 KB: col-half, both mats
    const int t    = threadIdx.x;
    const int wave = t >> 6, lane = t & 63;
    const int r = lane & 15, q = lane >> 4;
    const int rg = wave >> 1, cg2 = wave & 1; // 4 row-groups x 2 col-groups
    const int ch = blockIdx.x & 1;            // col-half
    const int p0 = (blockIdx.x >> 1) * 320;   // 125 chunks x 320 rows = 40000

    // ---- prologue: DMA W col-half into LDS, once. 64 chunks x 2 KB.
    // chunk c = (mat*8+kk)*4+qq ; src = Wt[(kk*2+mat)*4+qq] + ch*128 cols.
    {
        const char* WtB = (const char*)Wt;
        char* L = (char*)lw;
#pragma unroll
        for (int i = 0; i < 16; ++i) {
            int c = wave * 8 + (i >> 1);           // 0..63
            int d = i & 1;                          // half-chunk (1 KB)
            int mat = c >> 5, kk = (c >> 2) & 7, qq = c & 3;
            int src_sh = ((kk * 2 + mat) * 4 + qq) * 2048 + ch * 1024;
            dma16(WtB + (size_t)src_sh * 2 + d * 1024 + lane * 16,
                  L + (c * 2 + d) * 1024 + lane * 16);
        }
    }
    // bias regs for this wave's 64 cols
    const int cb = ch * 128 + cg2 * 64;
    float bfv[4], biv[4];
#pragma unroll
    for (int nt = 0; nt < 4; ++nt) {
        bfv[nt] = Bf[cb + nt * 16 + r];
        biv[nt] = Bi[cb + nt * 16 + r];
    }
    __syncthreads();                          // the ONLY barrier

    const short* bpf = lw + q * 1024 + (cg2 * 64 + r) * 8;  // mat f (Wf)
    const short* bpi = bpf + 32768;                          // mat i (Wi)

#pragma unroll
    for (int tt = 0; tt < 5; ++tt) {
        const int row = p0 + tt * 64 + rg * 16 + r;
        const short* x3r = (const short*)X3 + (size_t)row * DIM + q * 8;
        const float* rsr = RES + (size_t)row * DIM + q * 8;

        // burst-issue all A loads for this tile (24 loads), cvt deferred
        bf16x8 a1[8];
        float4 rw[16];
#pragma unroll
        for (int kk = 0; kk < 8; ++kk) {
            rw[2*kk]   = ((const float4*)rsr)[kk * 8];
            rw[2*kk+1] = ((const float4*)rsr)[kk * 8 + 1];
            a1[kk] = *(const bf16x8*)(x3r + kk * 32);
        }

        f32x4 acc1[4], acc2[4];
#pragma unroll
        for (int nt = 0; nt < 4; ++nt) {
            acc1[nt] = (f32x4){0.f,0.f,0.f,0.f};
            acc2[nt] = (f32x4){0.f,0.f,0.f,0.f};
        }
#pragma unroll
        for (int kk = 0; kk < 8; ++kk) {
            bf16x8 a2;
            {
                const float4 lo = rw[2*kk], hi2 = rw[2*kk+1];
                a2[0]=f2bs(lo.x);  a2[1]=f2bs(lo.y);  a2[2]=f2bs(lo.z);  a2[3]=f2bs(lo.w);
                a2[4]=f2bs(hi2.x); a2[5]=f2bs(hi2.y); a2[6]=f2bs(hi2.z); a2[7]=f2bs(hi2.w);
            }
#pragma unroll
            for (int nt = 0; nt < 4; ++nt) {
                bf16x8 b1 = *(const bf16x8*)(bpf + kk * 4096 + nt * 128);
                bf16x8 b2 = *(const bf16x8*)(bpi + kk * 4096 + nt * 128);
                acc1[nt] = __builtin_amdgcn_mfma_f32_16x16x32_bf16(a1[kk], b1, acc1[nt], 0, 0, 0);
                acc2[nt] = __builtin_amdgcn_mfma_f32_16x16x32_bf16(a2,    b2, acc2[nt], 0, 0, 0);
            }
        }
        // epilogue: 16 rows x 64 cols per wave
#pragma unroll
        for (int nt = 0; nt < 4; ++nt) {
            const int col = cb + nt * 16 + r;
#pragma unroll
            for (int i = 0; i < 4; ++i) {
                float v = lrelu(acc1[nt][i] + bfv[nt]) + lrelu(acc2[nt][i] + biv[nt]);
                OUT[(size_t)(p0 + tt * 64 + rg * 16 + q * 4 + i) * DIM + col] = v;
            }
        }
    }
}

// ---------------------------------------------------------------------------
extern "C" void kernel_launch(void* const* d_in, const int* in_sizes, int n_in,
                              void* d_out, int out_size, void* d_ws, size_t ws_size,
                              hipStream_t stream)
{
    const float* input  = (const float*)d_in[0];   // [2,20000,256]
    const float* geom   = (const float*)d_in[1];   // [2,20000,16,4]
    const int*   idxw   = (const int*)d_in[2];     // int32/int64 (detected)
    const float* W_init = (const float*)d_in[3];   // [64,256]
    const float* b_init = (const float*)d_in[4];
    const float* W_l1   = (const float*)d_in[5];   // [64,4]
    const float* b_l1   = (const float*)d_in[6];
    const float* W_l2   = (const float*)d_in[7];   // [128,4]
    const float* b_l2   = (const float*)d_in[8];
    const float* W_fin  = (const float*)d_in[9];   // [256,256]
    const float* b_fin  = (const float*)d_in[10];
    const float* W_id   = (const float*)d_in[11];  // [256,256]
    const float* b_id   = (const float*)d_in[12];
    float* out = (float*)d_out;                    // [2,20000,256] fp32

    // ws layout (<= 35.84 MB, proven safe R4-R21):
    //   flag @0 (16B)
    //   Wt  tiled bf16 256KB @16
    //   x2  [BN,128] bf16 @16+5.12e6
    //   x3  [BN,256] bf16 @16+15.36e6
    // x1 [BN,64] bf16 lives in d_out scratch; consumed by gatherA (g1), then
    // final_mfma overwrites all of d_out.
    char* ws = (char*)d_ws;
    int* flag = (int*)ws;
    short* Wt  = (short*)(ws + 16);
    __hip_bfloat16* x2 = (__hip_bfloat16*)(ws + 16 + 5120000);
    __hip_bfloat16* x3 = (__hip_bfloat16*)(ws + 16 + 15360000);
    __hip_bfloat16* x1 = (__hip_bfloat16*)d_out;   // scratch, dead after gatherA

    stage2_kernel<<<1379, 256, 0, stream>>>(geom, W_l1, b_l1, W_l2, b_l2,
                                            input, W_init, b_init,
                                            idxw, W_fin, W_id, Wt, flag,
                                            x2, x3, x1);
    gatherA_kernel<<<2500, 256, 0, stream>>>(idxw, flag, x1, x2, x3);
    gatherB_kernel<<<1250, 256, 0, stream>>>(idxw, flag, x2, x3);
    final_mfma<<<250, 512, 0, stream>>>(x3, input, Wt, b_fin, b_id, out);
}